// Round 1
// baseline (56526.666 us; speedup 1.0000x reference)
//
#include <hip/hip_runtime.h>
#include <stdint.h>

#define SEQ   16384
#define EMB   50
#define HID   300
#define G4    1200
#define NTAG  20
#define START 18
#define STOPT 19
#define NEGV  -10000.0f
#define NC    64
#define CH    256   // SEQ / NC

__device__ __forceinline__ float rcp_fast(float x){ return __builtin_amdgcn_rcpf(x); }
__device__ __forceinline__ float sigmoidf_(float x){ return rcp_fast(1.f + __expf(-x)); }
__device__ __forceinline__ float tanhf_fast(float x){
    float e = __expf(-2.f * fabsf(x));
    float r = (1.f - e) * rcp_fast(1.f + e);
    return copysignf(r, x);
}
__device__ __forceinline__ uint32_t f32_to_bf16(float f){
    uint32_t u = __float_as_uint(f);
    return (u + 0x7fffu + ((u >> 16) & 1u)) >> 16;   // RNE
}
__device__ __forceinline__ float bf16lo_to_f32(uint32_t pk){ return __uint_as_float(pk << 16); }
__device__ __forceinline__ float bf16hi_to_f32(uint32_t pk){ return __uint_as_float(pk & 0xffff0000u); }

// ---------------------------------------------------------------------------
// Phase A: xg[d][t][1200] (bf16) = emb[sent[t]] @ w_ih_d.T + b_ih_d + b_hh_d
// grid: 64 t-groups x 16 row-groups (8 per direction, 150 rows each); 256 thr
// ---------------------------------------------------------------------------
__global__ __launch_bounds__(256) void xg_kernel(
    const int* __restrict__ sent, const float* __restrict__ embed,
    const float* __restrict__ w_ih_f, const float* __restrict__ b_ih_f, const float* __restrict__ b_hh_f,
    const float* __restrict__ w_ih_b, const float* __restrict__ b_ih_b, const float* __restrict__ b_hh_b,
    uint16_t* __restrict__ xg)
{
    const int tg = blockIdx.x / 16;
    const int rg = blockIdx.x % 16;
    const int d  = rg / 8;
    const int rbase = (rg % 8) * 150;
    const int t = tg * 256 + threadIdx.x;

    const float* w_ih = d ? w_ih_b : w_ih_f;
    const float* b_ih = d ? b_ih_b : b_ih_f;
    const float* b_hh = d ? b_hh_b : b_hh_f;

    const int idx = sent[t];
    float e[EMB];
    const float* ep = embed + (size_t)idx * EMB;
    #pragma unroll
    for (int c = 0; c < EMB; c += 2){
        float2 v = *(const float2*)(ep + c);
        e[c] = v.x; e[c+1] = v.y;
    }
    uint16_t* outp = xg + ((size_t)d * SEQ + t) * G4 + rbase;
    #pragma unroll 1
    for (int rr = 0; rr < 150; rr += 2){
        float acc[2];
        #pragma unroll
        for (int k = 0; k < 2; k++){
            const int row = rbase + rr + k;
            const float* wr = w_ih + (size_t)row * EMB;
            float a0 = 0.f, a1 = 0.f;
            #pragma unroll
            for (int c = 0; c < EMB; c += 2){
                a0 += e[c]   * wr[c];
                a1 += e[c+1] * wr[c+1];
            }
            acc[k] = a0 + a1 + b_ih[row] + b_hh[row];
        }
        *(uint32_t*)(outp + rr) = f32_to_bf16(acc[0]) | (f32_to_bf16(acc[1]) << 16);
    }
}

// ---------------------------------------------------------------------------
// Phase B: persistent bidirectional LSTM. grid = 10 blocks (= 2 dir x 5 subs),
// 256 threads. Each block owns 60 hidden units (300 gate rows), weights in
// VGPRs (fp32, 300 regs/thread). Cross-block h exchange: u64 words with the
// step tag in the high half (single-copy atomic => no fences needed).
// ---------------------------------------------------------------------------
__global__ __launch_bounds__(256, 1) void lstm_kernel(
    const float* __restrict__ w_hh_f, const float* __restrict__ w_hh_b,
    const float* __restrict__ h0, const float* __restrict__ c0,
    const uint16_t* __restrict__ xg, uint32_t* __restrict__ hout,
    unsigned long long* hpub)
{
    const int d   = blockIdx.x / 5;
    const int sub = blockIdx.x % 5;
    const int u0  = sub * 60;
    const int tid = threadIdx.x;

    __shared__ __align__(16) float hbuf[HID];
    __shared__ float pre[240];
    __shared__ float hsl[60];

    const float* w_hh = d ? w_hh_b : w_hh_f;
    unsigned long long* pub = hpub + (size_t)d * 2 * 160;

    float w[HID];
    int R = 0;
    if (tid < 240){
        R = (tid / 60) * HID + u0 + (tid % 60);
        const float* wr = w_hh + (size_t)R * HID;
        #pragma unroll
        for (int c2 = 0; c2 < HID; c2 += 2){
            float2 v = *(const float2*)(wr + c2);
            w[c2] = v.x; w[c2+1] = v.y;
        }
    }
    if (tid < 150){
        hbuf[2*tid]   = h0[d*HID + 2*tid];
        hbuf[2*tid+1] = h0[d*HID + 2*tid+1];
    }
    float cst = 0.f;
    if (tid < 60) cst = c0[d*HID + u0 + tid];
    __syncthreads();

    const uint16_t* xgd = xg + (size_t)d * SEQ * G4;
    uint16_t xnr = 0;
    if (tid < 240) xnr = xgd[(size_t)(d ? (SEQ-1) : 0) * G4 + R];

    #pragma unroll 1
    for (int s = 0; s < SEQ; s++){
        const int t = d ? (SEQ-1-s) : s;
        const float xv = __uint_as_float(((uint32_t)xnr) << 16);
        {   // prefetch next step's xg (latency hidden by this step)
            const int s2 = (s+1 < SEQ) ? (s+1) : s;
            const int t2 = d ? (SEQ-1-s2) : s2;
            if (tid < 240) xnr = xgd[(size_t)t2 * G4 + R];
        }
        if (tid < 240){
            float a0 = xv, a1 = 0.f, a2 = 0.f, a3 = 0.f;
            #pragma unroll
            for (int c2 = 0; c2 < HID; c2 += 4){
                a0 += w[c2]   * hbuf[c2];
                a1 += w[c2+1] * hbuf[c2+1];
                a2 += w[c2+2] * hbuf[c2+2];
                a3 += w[c2+3] * hbuf[c2+3];
            }
            pre[tid] = (a0 + a1) + (a2 + a3);
        }
        __syncthreads();
        if (tid < 60){
            const float gi = sigmoidf_(pre[tid]);
            const float gf = sigmoidf_(pre[60  + tid]);
            const float gg = tanhf_fast(pre[120 + tid]);
            const float go = sigmoidf_(pre[180 + tid]);
            cst = gf * cst + gi * gg;
            hsl[tid] = go * tanhf_fast(cst);
        }
        __syncthreads();
        if (tid < 30){
            const uint32_t pk = f32_to_bf16(hsl[2*tid]) | (f32_to_bf16(hsl[2*tid+1]) << 16);
            hout[((size_t)d * SEQ + t) * 150 + (u0/2 + tid)] = pk;
            const unsigned long long val = (((unsigned long long)(unsigned)(s+1)) << 32) | pk;
            __hip_atomic_store(&pub[(size_t)(s & 1) * 160 + (u0/2 + tid)], val,
                               __ATOMIC_RELAXED, __HIP_MEMORY_SCOPE_AGENT);
        }
        if (tid < 150){
            unsigned long long* sp = &pub[(size_t)(s & 1) * 160 + tid];
            unsigned long long v;
            do {
                v = __hip_atomic_load(sp, __ATOMIC_RELAXED, __HIP_MEMORY_SCOPE_AGENT);
            } while ((unsigned)(v >> 32) != (unsigned)(s + 1));
            const uint32_t pk = (uint32_t)v;
            hbuf[2*tid]   = bf16lo_to_f32(pk);
            hbuf[2*tid+1] = bf16hi_to_f32(pk);
        }
        __syncthreads();
    }
}

// ---------------------------------------------------------------------------
// Phase C: feats[t][j] = [hf,hb] @ w_tag.T + b_tag. 256 blocks x 256 thr.
// ---------------------------------------------------------------------------
__global__ __launch_bounds__(256) void feats_kernel(
    const uint32_t* __restrict__ hout, const float* __restrict__ w_tag,
    const float* __restrict__ b_tag, float* __restrict__ feats)
{
    const int tl = threadIdx.x & 63;
    const int jg = threadIdx.x >> 6;
    const int t  = blockIdx.x * 64 + tl;
    float acc[5] = {0.f,0.f,0.f,0.f,0.f};
    #pragma unroll 1
    for (int dd = 0; dd < 2; dd++){
        const uint32_t* hp = hout + ((size_t)dd * SEQ + t) * 150;
        #pragma unroll 1
        for (int kw = 0; kw < 150; kw++){
            const uint32_t pk = hp[kw];
            const float hl = bf16lo_to_f32(pk);
            const float hh = bf16hi_to_f32(pk);
            #pragma unroll
            for (int jj = 0; jj < 5; jj++){
                const float* wrow = w_tag + (size_t)(jg*5 + jj) * 600 + dd*300 + 2*kw;
                acc[jj] += hl * wrow[0] + hh * wrow[1];
            }
        }
    }
    #pragma unroll
    for (int jj = 0; jj < 5; jj++)
        feats[(size_t)t * NTAG + jg*5 + jj] = acc[jj] + b_tag[jg*5 + jj];
}

// ---------------------------------------------------------------------------
// K1: per-chunk tropical (max-plus) matrix F_c. 64 blocks x 512 thr.
// ---------------------------------------------------------------------------
__global__ __launch_bounds__(512) void k1_chunkmat(
    const float* __restrict__ feats, const float* __restrict__ trans, float* __restrict__ Fc)
{
    const int c = blockIdx.x;
    const int tid = threadIdx.x;
    __shared__ float fl[CH * NTAG];
    __shared__ float M[2][NTAG * NTAG];
    for (int i = tid; i < CH*NTAG; i += 512) fl[i] = feats[(size_t)c * CH * NTAG + i];
    const int j = tid / NTAG, p = tid % NTAG;
    float tr[NTAG];
    if (tid < 400){
        #pragma unroll
        for (int q = 0; q < NTAG; q++) tr[q] = trans[j*NTAG + q];
        M[0][tid] = (j == p) ? 0.f : -1e30f;
    }
    __syncthreads();
    #pragma unroll 1
    for (int t = 0; t < CH; t++){
        const int cur = t & 1, nxt = cur ^ 1;
        if (tid < 400){
            float best = -1e38f;
            #pragma unroll
            for (int q = 0; q < NTAG; q++)
                best = fmaxf(best, tr[q] + M[cur][q*NTAG + p]);
            M[nxt][tid] = best + fl[t*NTAG + j];
        }
        __syncthreads();
    }
    if (tid < 400) Fc[(size_t)c * 400 + tid] = M[CH & 1][tid];
}

// K2: sequential scan of 64 chunk matrices -> fv at each chunk start + score.
__global__ __launch_bounds__(64) void k2_scan(
    const float* __restrict__ Fc, const float* __restrict__ trans,
    float* __restrict__ fvb, float* __restrict__ score_out, int* __restrict__ bestbuf)
{
    const int j = threadIdx.x;
    const bool act = j < NTAG;
    float fv = (j == START) ? 0.f : NEGV;
    #pragma unroll 1
    for (int c = 0; c < NC; c++){
        if (act) fvb[c*NTAG + j] = fv;
        float best = -1e38f;
        #pragma unroll
        for (int q = 0; q < NTAG; q++){
            const float fq = __shfl(fv, q, 64);
            if (act) best = fmaxf(best, Fc[(size_t)c*400 + j*NTAG + q] + fq);
        }
        fv = act ? best : NEGV;
    }
    const float term = act ? (fv + trans[STOPT*NTAG + j]) : -1e38f;
    float bs = -1e38f; int bi = 0;
    #pragma unroll
    for (int q = 0; q < NTAG; q++){
        const float v = __shfl(term, q, 64);
        if (v > bs){ bs = v; bi = q; }
    }
    if (j == 0){ score_out[0] = bs; bestbuf[0] = bi; }
}

// K3: per-chunk re-walk -> backpointers (global) + chunk backtrace map mu_c.
__global__ __launch_bounds__(64) void k3_bp(
    const float* __restrict__ feats, const float* __restrict__ trans,
    const float* __restrict__ fvb, uint8_t* __restrict__ bps, int* __restrict__ mu)
{
    const int c = blockIdx.x;
    const int j = threadIdx.x;
    const bool act = j < NTAG;
    __shared__ float fl[CH * NTAG];
    __shared__ uint8_t bp[CH * NTAG];
    for (int i = j; i < CH*NTAG; i += 64) fl[i] = feats[(size_t)c * CH * NTAG + i];
    float tr[NTAG];
    if (act){
        #pragma unroll
        for (int q = 0; q < NTAG; q++) tr[q] = trans[j*NTAG + q];
    }
    float fv = act ? fvb[c*NTAG + j] : NEGV;
    __syncthreads();
    #pragma unroll 1
    for (int t = 0; t < CH; t++){
        float best = -1e38f; int bi = 0;
        #pragma unroll
        for (int q = 0; q < NTAG; q++){
            const float fq = __shfl(fv, q, 64);
            if (act){
                const float v = tr[q] + fq;
                if (v > best){ best = v; bi = q; }   // strict > : first max (argmax semantics)
            }
        }
        if (act) bp[t*NTAG + j] = (uint8_t)bi;
        fv = act ? (best + fl[t*NTAG + j]) : NEGV;
    }
    __syncthreads();
    int m = act ? j : 0;
    #pragma unroll 1
    for (int t = CH-1; t >= 0; t--){
        if (act) m = bp[t*NTAG + m];
    }
    if (act) mu[c*NTAG + j] = m;
    for (int i = j; i < CH*NTAG; i += 64) bps[(size_t)c * CH * NTAG + i] = bp[i];
}

// K4: chunk-boundary tags (tiny sequential).
__global__ void k4_tags(const int* __restrict__ mu, const int* __restrict__ bestbuf,
                        int* __restrict__ tagend)
{
    if (threadIdx.x == 0 && blockIdx.x == 0){
        int g = bestbuf[0];
        tagend[NC-1] = g;
        for (int c = NC-1; c >= 1; c--){ g = mu[c*NTAG + g]; tagend[c-1] = g; }
    }
}

// K5: per-chunk path fill -> d_out[1..SEQ] as f32 tags.
__global__ __launch_bounds__(64) void k5_path(
    const uint8_t* __restrict__ bps, const int* __restrict__ tagend, float* __restrict__ outpath)
{
    const int c = blockIdx.x;
    const int tid = threadIdx.x;
    __shared__ uint8_t bp[CH * NTAG];
    __shared__ float pl[CH];
    for (int i = tid; i < CH*NTAG; i += 64) bp[i] = bps[(size_t)c * CH * NTAG + i];
    __syncthreads();
    if (tid == 0){
        int g = tagend[c];
        pl[CH-1] = (float)g;
        for (int t = CH-1; t >= 1; t--){ g = bp[t*NTAG + g]; pl[t-1] = (float)g; }
    }
    __syncthreads();
    for (int i = tid; i < CH; i += 64) outpath[(size_t)c * CH + i] = pl[i];
}

// ---------------------------------------------------------------------------
extern "C" void kernel_launch(void* const* d_in, const int* in_sizes, int n_in,
                              void* d_out, int out_size, void* d_ws, size_t ws_size,
                              hipStream_t stream)
{
    const int*   sent    = (const int*)  d_in[0];
    const float* embed   = (const float*)d_in[1];
    const float* w_ih_f  = (const float*)d_in[2];
    const float* w_hh_f  = (const float*)d_in[3];
    const float* b_ih_f  = (const float*)d_in[4];
    const float* b_hh_f  = (const float*)d_in[5];
    const float* w_ih_b  = (const float*)d_in[6];
    const float* w_hh_b  = (const float*)d_in[7];
    const float* b_ih_b  = (const float*)d_in[8];
    const float* b_hh_b  = (const float*)d_in[9];
    const float* h0      = (const float*)d_in[10];
    const float* c0      = (const float*)d_in[11];
    const float* w_tag   = (const float*)d_in[12];
    const float* b_tag   = (const float*)d_in[13];
    const float* trans   = (const float*)d_in[14];
    float* out = (float*)d_out;

    char* ws = (char*)d_ws;
    size_t off = 0;
    auto alloc = [&](size_t bytes)->char*{
        char* p = ws + off; off += (bytes + 255) & ~(size_t)255; return p;
    };
    uint16_t* xg              = (uint16_t*)alloc(2ull * SEQ * G4 * 2);     // 78.6 MB
    uint32_t* hout            = (uint32_t*)alloc(2ull * SEQ * 150 * 4);    // 19.7 MB
    float*    feats           = (float*)   alloc((size_t)SEQ * NTAG * 4);  // 1.3 MB
    unsigned long long* hpub  = (unsigned long long*)alloc(2ull * 2 * 160 * 8);
    float*    Fc              = (float*)   alloc((size_t)NC * 400 * 4);
    float*    fvb             = (float*)   alloc((size_t)NC * NTAG * 4);
    uint8_t*  bps             = (uint8_t*) alloc((size_t)SEQ * NTAG);
    int*      mu              = (int*)     alloc((size_t)NC * NTAG * 4);
    int*      tagend          = (int*)     alloc((size_t)NC * 4);
    int*      bestbuf         = (int*)     alloc(256);

    hipLaunchKernelGGL(xg_kernel, dim3(1024), dim3(256), 0, stream,
                       sent, embed, w_ih_f, b_ih_f, b_hh_f, w_ih_b, b_ih_b, b_hh_b, xg);
    hipLaunchKernelGGL(lstm_kernel, dim3(10), dim3(256), 0, stream,
                       w_hh_f, w_hh_b, h0, c0, xg, hout, hpub);
    hipLaunchKernelGGL(feats_kernel, dim3(256), dim3(256), 0, stream,
                       hout, w_tag, b_tag, feats);
    hipLaunchKernelGGL(k1_chunkmat, dim3(NC), dim3(512), 0, stream, feats, trans, Fc);
    hipLaunchKernelGGL(k2_scan, dim3(1), dim3(64), 0, stream, Fc, trans, fvb, out, bestbuf);
    hipLaunchKernelGGL(k3_bp, dim3(NC), dim3(64), 0, stream, feats, trans, fvb, bps, mu);
    hipLaunchKernelGGL(k4_tags, dim3(1), dim3(64), 0, stream, mu, bestbuf, tagend);
    hipLaunchKernelGGL(k5_path, dim3(NC), dim3(64), 0, stream, bps, tagend, out + 1);
}

// Round 2
// 40152.802 us; speedup vs baseline: 1.4078x; 1.4078x over previous
//
#include <hip/hip_runtime.h>
#include <stdint.h>

#define SEQ   16384
#define EMB   50
#define HID   300
#define G4    1200
#define NTAG  20
#define START 18
#define STOPT 19
#define NEGV  -10000.0f
#define NC    64
#define CH    256   // SEQ / NC

__device__ __forceinline__ float rcp_fast(float x){ return __builtin_amdgcn_rcpf(x); }
__device__ __forceinline__ float sigmoidf_(float x){ return rcp_fast(1.f + __expf(-x)); }
__device__ __forceinline__ float tanhf_fast(float x){
    float e = __expf(-2.f * fabsf(x));
    float r = (1.f - e) * rcp_fast(1.f + e);
    return copysignf(r, x);
}
__device__ __forceinline__ uint32_t f32_to_bf16(float f){
    uint32_t u = __float_as_uint(f);
    return (u + 0x7fffu + ((u >> 16) & 1u)) >> 16;   // RNE
}
__device__ __forceinline__ float bf16lo_to_f32(uint32_t pk){ return __uint_as_float(pk << 16); }
__device__ __forceinline__ float bf16hi_to_f32(uint32_t pk){ return __uint_as_float(pk & 0xffff0000u); }

// ---------------------------------------------------------------------------
// Phase A: xg[d][t][1200] (bf16) = emb[sent[t]] @ w_ih_d.T + b_ih_d + b_hh_d
// ---------------------------------------------------------------------------
__global__ __launch_bounds__(256) void xg_kernel(
    const int* __restrict__ sent, const float* __restrict__ embed,
    const float* __restrict__ w_ih_f, const float* __restrict__ b_ih_f, const float* __restrict__ b_hh_f,
    const float* __restrict__ w_ih_b, const float* __restrict__ b_ih_b, const float* __restrict__ b_hh_b,
    uint16_t* __restrict__ xg)
{
    const int tg = blockIdx.x / 16;
    const int rg = blockIdx.x % 16;
    const int d  = rg / 8;
    const int rbase = (rg % 8) * 150;
    const int t = tg * 256 + threadIdx.x;

    const float* w_ih = d ? w_ih_b : w_ih_f;
    const float* b_ih = d ? b_ih_b : b_ih_f;
    const float* b_hh = d ? b_hh_b : b_hh_f;

    const int idx = sent[t];
    float e[EMB];
    const float* ep = embed + (size_t)idx * EMB;
    #pragma unroll
    for (int c = 0; c < EMB; c += 2){
        float2 v = *(const float2*)(ep + c);
        e[c] = v.x; e[c+1] = v.y;
    }
    uint16_t* outp = xg + ((size_t)d * SEQ + t) * G4 + rbase;
    #pragma unroll 1
    for (int rr = 0; rr < 150; rr += 2){
        float acc[2];
        #pragma unroll
        for (int k = 0; k < 2; k++){
            const int row = rbase + rr + k;
            const float* wr = w_ih + (size_t)row * EMB;
            float a0 = 0.f, a1 = 0.f;
            #pragma unroll
            for (int c = 0; c < EMB; c += 2){
                a0 += e[c]   * wr[c];
                a1 += e[c+1] * wr[c+1];
            }
            acc[k] = a0 + a1 + b_ih[row] + b_hh[row];
        }
        *(uint32_t*)(outp + rr) = f32_to_bf16(acc[0]) | (f32_to_bf16(acc[1]) << 16);
    }
}

// ---------------------------------------------------------------------------
// Phase B: persistent bidirectional LSTM. grid = 10 blocks (2 dir x 5 subs),
// 512 threads. Block owns 60 hidden units = 240 gate rows. Each row's K=300
// dot is split across a thread PAIR (150 f32 weights per thread -> no spill;
// VGPR budget 256 at __launch_bounds__(512,2)). Partials combine via
// __shfl_xor(.,1). Cross-block h exchange: tagged u64 words, relaxed agent
// atomics; own slice copied locally, only remote words polled.
// ---------------------------------------------------------------------------
__global__ __launch_bounds__(512, 2) void lstm_kernel(
    const float* __restrict__ w_hh_f, const float* __restrict__ w_hh_b,
    const float* __restrict__ h0, const float* __restrict__ c0,
    const uint16_t* __restrict__ xg, uint32_t* __restrict__ hout,
    unsigned long long* hpub)
{
    const int d   = blockIdx.x / 5;
    const int sub = blockIdx.x % 5;
    const int u0  = sub * 60;
    const int tid = threadIdx.x;

    __shared__ __align__(16) float hbuf[HID];
    __shared__ float pre[240];
    __shared__ float hsl[60];

    const float* w_hh = d ? w_hh_b : w_hh_f;
    unsigned long long* pub = hpub + (size_t)d * 2 * 160;

    const bool act  = tid < 480;          // dot-product workers
    const int  row  = tid >> 1;           // 0..239
    const int  half = tid & 1;            // K half: [0,150) or [150,300)
    const int  R    = act ? ((row / 60) * HID + u0 + (row % 60)) : 0;

    // 150 f32 weights per thread (this row's K-half) — stays in VGPRs.
    float w[150];
    if (act){
        const float* wr = w_hh + (size_t)R * HID + half * 150;
        #pragma unroll
        for (int i = 0; i < 150; i += 2){
            float2 v = *(const float2*)(wr + i);
            w[i] = v.x; w[i+1] = v.y;
        }
    }
    if (tid < 150){
        hbuf[2*tid]   = h0[d*HID + 2*tid];
        hbuf[2*tid+1] = h0[d*HID + 2*tid+1];
    }
    float cst = 0.f;
    if (tid < 60) cst = c0[d*HID + u0 + tid];
    __syncthreads();

    const uint16_t* xgd = xg + (size_t)d * SEQ * G4;
    const bool xldr = act && (half == 0);   // even thread of each pair loads xg[row]
    uint16_t xnr = 0;
    if (xldr) xnr = xgd[(size_t)(d ? (SEQ-1) : 0) * G4 + R];

    const int myw0 = u0 / 2;                // own packed-word range [myw0, myw0+30)
    const bool pollme = (tid < 150) && (tid < myw0 || tid >= myw0 + 30);

    #pragma unroll 1
    for (int s = 0; s < SEQ; s++){
        const int t = d ? (SEQ-1-s) : s;
        const float xv = __uint_as_float(((uint32_t)xnr) << 16);
        {   // prefetch next step's xg (latency hidden by this step)
            const int s2 = (s+1 < SEQ) ? (s+1) : s;
            const int t2 = d ? (SEQ-1-s2) : s2;
            if (xldr) xnr = xgd[(size_t)t2 * G4 + R];
        }
        if (act){
            const float* hb = hbuf + half * 150;
            float a0 = (half == 0) ? xv : 0.f;
            float a1 = 0.f;
            #pragma unroll
            for (int i = 0; i < 150; i += 2){
                a0 += w[i]   * hb[i];
                a1 += w[i+1] * hb[i+1];
            }
            float a = a0 + a1;
            a += __shfl_xor(a, 1);
            if (half == 0) pre[row] = a;
        }
        __syncthreads();
        if (tid < 60){
            const float gi = sigmoidf_(pre[tid]);
            const float gf = sigmoidf_(pre[60  + tid]);
            const float gg = tanhf_fast(pre[120 + tid]);
            const float go = sigmoidf_(pre[180 + tid]);
            cst = gf * cst + gi * gg;
            const float hv = go * tanhf_fast(cst);
            hsl[tid] = hv;
            hbuf[u0 + tid] = hv;           // own slice: local copy, no global RT
        }
        __syncthreads();
        if (tid < 30){
            const uint32_t pk = f32_to_bf16(hsl[2*tid]) | (f32_to_bf16(hsl[2*tid+1]) << 16);
            hout[((size_t)d * SEQ + t) * 150 + (myw0 + tid)] = pk;
            const unsigned long long val = (((unsigned long long)(unsigned)(s+1)) << 32) | pk;
            __hip_atomic_store(&pub[(size_t)(s & 1) * 160 + (myw0 + tid)], val,
                               __ATOMIC_RELAXED, __HIP_MEMORY_SCOPE_AGENT);
        }
        if (pollme){
            unsigned long long* sp = &pub[(size_t)(s & 1) * 160 + tid];
            unsigned long long v;
            do {
                v = __hip_atomic_load(sp, __ATOMIC_RELAXED, __HIP_MEMORY_SCOPE_AGENT);
            } while ((unsigned)(v >> 32) != (unsigned)(s + 1));
            const uint32_t pk = (uint32_t)v;
            hbuf[2*tid]   = bf16lo_to_f32(pk);
            hbuf[2*tid+1] = bf16hi_to_f32(pk);
        }
        __syncthreads();
    }
}

// ---------------------------------------------------------------------------
// Phase C: feats[t][j] = [hf,hb] @ w_tag.T + b_tag. 256 blocks x 256 thr.
// ---------------------------------------------------------------------------
__global__ __launch_bounds__(256) void feats_kernel(
    const uint32_t* __restrict__ hout, const float* __restrict__ w_tag,
    const float* __restrict__ b_tag, float* __restrict__ feats)
{
    const int tl = threadIdx.x & 63;
    const int jg = threadIdx.x >> 6;
    const int t  = blockIdx.x * 64 + tl;
    float acc[5] = {0.f,0.f,0.f,0.f,0.f};
    #pragma unroll 1
    for (int dd = 0; dd < 2; dd++){
        const uint32_t* hp = hout + ((size_t)dd * SEQ + t) * 150;
        #pragma unroll 1
        for (int kw = 0; kw < 150; kw++){
            const uint32_t pk = hp[kw];
            const float hl = bf16lo_to_f32(pk);
            const float hh = bf16hi_to_f32(pk);
            #pragma unroll
            for (int jj = 0; jj < 5; jj++){
                const float* wrow = w_tag + (size_t)(jg*5 + jj) * 600 + dd*300 + 2*kw;
                acc[jj] += hl * wrow[0] + hh * wrow[1];
            }
        }
    }
    #pragma unroll
    for (int jj = 0; jj < 5; jj++)
        feats[(size_t)t * NTAG + jg*5 + jj] = acc[jj] + b_tag[jg*5 + jj];
}

// ---------------------------------------------------------------------------
// K1: per-chunk tropical (max-plus) matrix F_c. 64 blocks x 512 thr.
// ---------------------------------------------------------------------------
__global__ __launch_bounds__(512) void k1_chunkmat(
    const float* __restrict__ feats, const float* __restrict__ trans, float* __restrict__ Fc)
{
    const int c = blockIdx.x;
    const int tid = threadIdx.x;
    __shared__ float fl[CH * NTAG];
    __shared__ float M[2][NTAG * NTAG];
    for (int i = tid; i < CH*NTAG; i += 512) fl[i] = feats[(size_t)c * CH * NTAG + i];
    const int j = tid / NTAG, p = tid % NTAG;
    float tr[NTAG];
    if (tid < 400){
        #pragma unroll
        for (int q = 0; q < NTAG; q++) tr[q] = trans[j*NTAG + q];
        M[0][tid] = (j == p) ? 0.f : -1e30f;
    }
    __syncthreads();
    #pragma unroll 1
    for (int t = 0; t < CH; t++){
        const int cur = t & 1, nxt = cur ^ 1;
        if (tid < 400){
            float best = -1e38f;
            #pragma unroll
            for (int q = 0; q < NTAG; q++)
                best = fmaxf(best, tr[q] + M[cur][q*NTAG + p]);
            M[nxt][tid] = best + fl[t*NTAG + j];
        }
        __syncthreads();
    }
    if (tid < 400) Fc[(size_t)c * 400 + tid] = M[CH & 1][tid];
}

// K2: sequential scan of 64 chunk matrices -> fv at each chunk start + score.
__global__ __launch_bounds__(64) void k2_scan(
    const float* __restrict__ Fc, const float* __restrict__ trans,
    float* __restrict__ fvb, float* __restrict__ score_out, int* __restrict__ bestbuf)
{
    const int j = threadIdx.x;
    const bool act = j < NTAG;
    float fv = (j == START) ? 0.f : NEGV;
    #pragma unroll 1
    for (int c = 0; c < NC; c++){
        if (act) fvb[c*NTAG + j] = fv;
        float best = -1e38f;
        #pragma unroll
        for (int q = 0; q < NTAG; q++){
            const float fq = __shfl(fv, q, 64);
            if (act) best = fmaxf(best, Fc[(size_t)c*400 + j*NTAG + q] + fq);
        }
        fv = act ? best : NEGV;
    }
    const float term = act ? (fv + trans[STOPT*NTAG + j]) : -1e38f;
    float bs = -1e38f; int bi = 0;
    #pragma unroll
    for (int q = 0; q < NTAG; q++){
        const float v = __shfl(term, q, 64);
        if (v > bs){ bs = v; bi = q; }
    }
    if (j == 0){ score_out[0] = bs; bestbuf[0] = bi; }
}

// K3: per-chunk re-walk -> backpointers (global) + chunk backtrace map mu_c.
__global__ __launch_bounds__(64) void k3_bp(
    const float* __restrict__ feats, const float* __restrict__ trans,
    const float* __restrict__ fvb, uint8_t* __restrict__ bps, int* __restrict__ mu)
{
    const int c = blockIdx.x;
    const int j = threadIdx.x;
    const bool act = j < NTAG;
    __shared__ float fl[CH * NTAG];
    __shared__ uint8_t bp[CH * NTAG];
    for (int i = j; i < CH*NTAG; i += 64) fl[i] = feats[(size_t)c * CH * NTAG + i];
    float tr[NTAG];
    if (act){
        #pragma unroll
        for (int q = 0; q < NTAG; q++) tr[q] = trans[j*NTAG + q];
    }
    float fv = act ? fvb[c*NTAG + j] : NEGV;
    __syncthreads();
    #pragma unroll 1
    for (int t = 0; t < CH; t++){
        float best = -1e38f; int bi = 0;
        #pragma unroll
        for (int q = 0; q < NTAG; q++){
            const float fq = __shfl(fv, q, 64);
            if (act){
                const float v = tr[q] + fq;
                if (v > best){ best = v; bi = q; }   // strict > : first max (argmax semantics)
            }
        }
        if (act) bp[t*NTAG + j] = (uint8_t)bi;
        fv = act ? (best + fl[t*NTAG + j]) : NEGV;
    }
    __syncthreads();
    int m = act ? j : 0;
    #pragma unroll 1
    for (int t = CH-1; t >= 0; t--){
        if (act) m = bp[t*NTAG + m];
    }
    if (act) mu[c*NTAG + j] = m;
    for (int i = j; i < CH*NTAG; i += 64) bps[(size_t)c * CH * NTAG + i] = bp[i];
}

// K4: chunk-boundary tags (tiny sequential).
__global__ void k4_tags(const int* __restrict__ mu, const int* __restrict__ bestbuf,
                        int* __restrict__ tagend)
{
    if (threadIdx.x == 0 && blockIdx.x == 0){
        int g = bestbuf[0];
        tagend[NC-1] = g;
        for (int c = NC-1; c >= 1; c--){ g = mu[c*NTAG + g]; tagend[c-1] = g; }
    }
}

// K5: per-chunk path fill -> d_out[1..SEQ] as f32 tags.
__global__ __launch_bounds__(64) void k5_path(
    const uint8_t* __restrict__ bps, const int* __restrict__ tagend, float* __restrict__ outpath)
{
    const int c = blockIdx.x;
    const int tid = threadIdx.x;
    __shared__ uint8_t bp[CH * NTAG];
    __shared__ float pl[CH];
    for (int i = tid; i < CH*NTAG; i += 64) bp[i] = bps[(size_t)c * CH * NTAG + i];
    __syncthreads();
    if (tid == 0){
        int g = tagend[c];
        pl[CH-1] = (float)g;
        for (int t = CH-1; t >= 1; t--){ g = bp[t*NTAG + g]; pl[t-1] = (float)g; }
    }
    __syncthreads();
    for (int i = tid; i < CH; i += 64) outpath[(size_t)c * CH + i] = pl[i];
}

// ---------------------------------------------------------------------------
extern "C" void kernel_launch(void* const* d_in, const int* in_sizes, int n_in,
                              void* d_out, int out_size, void* d_ws, size_t ws_size,
                              hipStream_t stream)
{
    const int*   sent    = (const int*)  d_in[0];
    const float* embed   = (const float*)d_in[1];
    const float* w_ih_f  = (const float*)d_in[2];
    const float* w_hh_f  = (const float*)d_in[3];
    const float* b_ih_f  = (const float*)d_in[4];
    const float* b_hh_f  = (const float*)d_in[5];
    const float* w_ih_b  = (const float*)d_in[6];
    const float* w_hh_b  = (const float*)d_in[7];
    const float* b_ih_b  = (const float*)d_in[8];
    const float* b_hh_b  = (const float*)d_in[9];
    const float* h0      = (const float*)d_in[10];
    const float* c0      = (const float*)d_in[11];
    const float* w_tag   = (const float*)d_in[12];
    const float* b_tag   = (const float*)d_in[13];
    const float* trans   = (const float*)d_in[14];
    float* out = (float*)d_out;

    char* ws = (char*)d_ws;
    size_t off = 0;
    auto alloc = [&](size_t bytes)->char*{
        char* p = ws + off; off += (bytes + 255) & ~(size_t)255; return p;
    };
    uint16_t* xg              = (uint16_t*)alloc(2ull * SEQ * G4 * 2);     // 78.6 MB
    uint32_t* hout            = (uint32_t*)alloc(2ull * SEQ * 150 * 4);    // 19.7 MB
    float*    feats           = (float*)   alloc((size_t)SEQ * NTAG * 4);  // 1.3 MB
    unsigned long long* hpub  = (unsigned long long*)alloc(2ull * 2 * 160 * 8);
    float*    Fc              = (float*)   alloc((size_t)NC * 400 * 4);
    float*    fvb             = (float*)   alloc((size_t)NC * NTAG * 4);
    uint8_t*  bps             = (uint8_t*) alloc((size_t)SEQ * NTAG);
    int*      mu              = (int*)     alloc((size_t)NC * NTAG * 4);
    int*      tagend          = (int*)     alloc((size_t)NC * 4);
    int*      bestbuf         = (int*)     alloc(256);

    hipLaunchKernelGGL(xg_kernel, dim3(1024), dim3(256), 0, stream,
                       sent, embed, w_ih_f, b_ih_f, b_hh_f, w_ih_b, b_ih_b, b_hh_b, xg);
    hipLaunchKernelGGL(lstm_kernel, dim3(10), dim3(512), 0, stream,
                       w_hh_f, w_hh_b, h0, c0, xg, hout, hpub);
    hipLaunchKernelGGL(feats_kernel, dim3(256), dim3(256), 0, stream,
                       hout, w_tag, b_tag, feats);
    hipLaunchKernelGGL(k1_chunkmat, dim3(NC), dim3(512), 0, stream, feats, trans, Fc);
    hipLaunchKernelGGL(k2_scan, dim3(1), dim3(64), 0, stream, Fc, trans, fvb, out, bestbuf);
    hipLaunchKernelGGL(k3_bp, dim3(NC), dim3(64), 0, stream, feats, trans, fvb, bps, mu);
    hipLaunchKernelGGL(k4_tags, dim3(1), dim3(64), 0, stream, mu, bestbuf, tagend);
    hipLaunchKernelGGL(k5_path, dim3(NC), dim3(64), 0, stream, bps, tagend, out + 1);
}